// Round 1
// baseline (1328.729 us; speedup 1.0000x reference)
//
#include <hip/hip_runtime.h>

#define HA 256
#define WA 256
#define HB 128
#define WB 128
#define PA 48
#define PB 48
#define PP 96
#define MM 32
#define NPIXA (HA*WA)   // 65536
#define NPIXB (HB*WB)   // 16384

__device__ __forceinline__ float gelu_f(float x) {
    // 0.5x(1+tanh(k(x+0.044715x^3))) == x*e/(e+1) with e=exp(2z); use x - x/(e+1) (inf-safe)
    float z = 0.7978845608028654f * (x + 0.044715f * x * x * x);
    float e = __expf(2.0f * z);
    return x - x / (e + 1.0f);
}

// ---------------- DFT twiddle tables ----------------
__global__ __launch_bounds__(256) void k_gen_tables(
        float* tfxA, float* tfyA, float* tixA, float* tiyA,
        float* tfxB, float* tfyB, float* tixB, float* tiyB) {
    const float TWO_PI = 6.28318530717958647692f;
    int t = blockIdx.x * 256 + threadIdx.x;
    if (t < MM * WA) {
        int k = t / WA, x = t - k * WA;
        int m = (k * x) & (WA - 1);
        float ang = TWO_PI * (float)m / (float)WA;
        float s, c; __sincosf(ang, &s, &c);
        float sc = 1.0f / (float)(HA * WA);
        tfxA[2*t] = c * sc; tfxA[2*t+1] = -s * sc;     // e^{-i ang} * (1/(H*W))
        float wgt = (k == 0) ? 1.0f : 2.0f;
        tixA[2*t] = wgt * c; tixA[2*t+1] = wgt * s;    // w * e^{+i ang}
        int ky = k - 16;                                // centered freqs, j-16
        int my = (ky * x) & (HA - 1);                  // two's complement & = mod for pow2
        float angy = TWO_PI * (float)my / (float)HA;
        float sy, cy; __sincosf(angy, &sy, &cy);
        tfyA[2*t] = cy; tfyA[2*t+1] = -sy;
        tiyA[2*t] = cy; tiyA[2*t+1] = sy;
    } else if (t < MM * WA + MM * WB) {
        int t2 = t - MM * WA;
        int k = t2 / WB, x = t2 - k * WB;
        int m = (k * x) & (WB - 1);
        float ang = TWO_PI * (float)m / (float)WB;
        float s, c; __sincosf(ang, &s, &c);
        float sc = 1.0f / (float)(HB * WB);
        tfxB[2*t2] = c * sc; tfxB[2*t2+1] = -s * sc;
        float wgt = (k == 0) ? 1.0f : 2.0f;
        tixB[2*t2] = wgt * c; tixB[2*t2+1] = wgt * s;
        int ky = k - 16;
        int my = (ky * x) & (HB - 1);
        float angy = TWO_PI * (float)my / (float)HB;
        float sy, cy; __sincosf(angy, &sy, &cy);
        tfyB[2*t2] = cy; tfyB[2*t2+1] = -sy;
        tiyB[2*t2] = cy; tiyB[2*t2+1] = sy;
    }
}

// ---------------- encoder (1x1 conv, 3->48) ----------------
__global__ __launch_bounds__(256) void k_encode(
        const float* u_a, const float* x_a, const float* u_b, const float* x_b,
        const float* wa, const float* ba, const float* wb, const float* bb,
        float* UA, float* UB) {
    int o = blockIdx.y;
    if (blockIdx.x < NPIXA/256) {
        int pix = blockIdx.x * 256 + threadIdx.x;
        UA[(size_t)o*NPIXA + pix] = wa[o*3+0]*x_a[pix] + wa[o*3+1]*x_a[NPIXA+pix]
                                  + wa[o*3+2]*u_a[pix] + ba[o];
    } else {
        int pix = (blockIdx.x - NPIXA/256) * 256 + threadIdx.x;
        UB[(size_t)o*NPIXB + pix] = wb[o*3+0]*x_b[pix] + wb[o*3+1]*x_b[NPIXB+pix]
                                  + wb[o*3+2]*u_b[pix] + bb[o];
    }
}

// ---------------- forward DFT along x: U(r, x) -> F(r, kx) complex ----------------
// block: 32 rows staged in LDS; thread = (kx, rowgroup of 4)
__global__ __launch_bounds__(256) void k_fwd_x(
        const float* UA, const float* UB, float2* FA, float2* FB,
        const float* tfxA, const float* tfxB) {
    extern __shared__ float ls[];
    int bid = blockIdx.x;
    const float* U; float2* F; const float2* tab; int N;
    const int NBA = PA * HA / 32;   // 384
    if (bid < NBA) { U = UA; F = FA; tab = (const float2*)tfxA; N = WA; }
    else { bid -= NBA; U = UB; F = FB; tab = (const float2*)tfxB; N = WB; }
    int r0 = bid * 32;
    int tot4 = 32 * N / 4;
    const float4* src = (const float4*)(U + (size_t)r0 * N);
    for (int i = threadIdx.x; i < tot4; i += 256) ((float4*)ls)[i] = src[i];
    __syncthreads();
    int kx = threadIdx.x & 31;
    int rg = (threadIdx.x >> 5) * 4;
    float ar0=0,ai0=0,ar1=0,ai1=0,ar2=0,ai2=0,ar3=0,ai3=0;
    const float2* tk = tab + kx * N;
    for (int x = 0; x < N; ++x) {
        float2 t = tk[x];
        float u0 = ls[(rg+0)*N + x];
        float u1 = ls[(rg+1)*N + x];
        float u2 = ls[(rg+2)*N + x];
        float u3 = ls[(rg+3)*N + x];
        ar0 += u0*t.x; ai0 += u0*t.y;
        ar1 += u1*t.x; ai1 += u1*t.y;
        ar2 += u2*t.x; ai2 += u2*t.y;
        ar3 += u3*t.x; ai3 += u3*t.y;
    }
    F[(size_t)(r0+rg+0)*MM + kx] = make_float2(ar0, ai0);
    F[(size_t)(r0+rg+1)*MM + kx] = make_float2(ar1, ai1);
    F[(size_t)(r0+rg+2)*MM + kx] = make_float2(ar2, ai2);
    F[(size_t)(r0+rg+3)*MM + kx] = make_float2(ar3, ai3);
}

// ---------------- forward DFT along y: F(c,y,kx) -> CIN(p, j, kx) ----------------
__global__ __launch_bounds__(256) void k_fwd_y(
        const float2* FA, const float2* FB, float2* CIN,
        const float* tfyA, const float* tfyB) {
    int bid = blockIdx.x;
    const float2* F; const float2* tab; int Ny, pbase;
    if (bid < PA*4) { F = FA; tab = (const float2*)tfyA; Ny = HA; pbase = 0; }
    else { bid -= PA*4; F = FB; tab = (const float2*)tfyB; Ny = HB; pbase = PA; }
    int c = bid >> 2;
    int j = (bid & 3) * 8 + (threadIdx.x >> 5);
    int kx = threadIdx.x & 31;
    float re = 0.f, im = 0.f;
    const float2* fr = F + (size_t)c * Ny * MM + kx;
    const float2* tj = tab + j * Ny;
    #pragma unroll 4
    for (int y = 0; y < Ny; ++y) {
        float2 f = fr[y * MM];
        float2 t = tj[y];
        re += f.x*t.x - f.y*t.y;
        im += f.x*t.y + f.y*t.x;
    }
    CIN[((pbase + c)*MM + j)*MM + kx] = make_float2(re, im);
}

// ---------------- spectral channel mix: 96x96 complex per mode ----------------
__global__ __launch_bounds__(256) void k_spectral(
        const float* Wre, const float* Wim, const float2* CIN, float2* COUT) {
    int t = blockIdx.x * 256 + threadIdx.x;
    int p = t >> 10;
    int mode = t & 1023;
    const float* wr = Wre + (size_t)p * PP * 1024 + mode;
    const float* wi = Wim + (size_t)p * PP * 1024 + mode;
    float re = 0.f, im = 0.f;
    #pragma unroll 4
    for (int q = 0; q < PP; ++q) {
        float a = wr[(size_t)q * 1024];
        float b = wi[(size_t)q * 1024];
        float2 cv = CIN[q * 1024 + mode];
        re += a*cv.x - b*cv.y;
        im += a*cv.y + b*cv.x;
    }
    COUT[p * 1024 + mode] = make_float2(re, im);
}

// ---------------- inverse DFT along y: COUT(p,j,kx) -> D(c,y,kx) ----------------
__global__ __launch_bounds__(256) void k_inv_y(
        const float2* COUT, float2* DA, float2* DB,
        const float* tiyA, const float* tiyB) {
    int bid = blockIdx.x;
    float2* D; const float2* tab; int Ny, pbase, c, yg;
    if (bid < PA*(HA/8)) { D = DA; tab = (const float2*)tiyA; Ny = HA; pbase = 0;
        c = bid >> 5; yg = bid & 31; }
    else { bid -= PA*(HA/8); D = DB; tab = (const float2*)tiyB; Ny = HB; pbase = PA;
        c = bid >> 4; yg = bid & 15; }
    int kx = threadIdx.x & 31;
    int y = yg * 8 + (threadIdx.x >> 5);
    float re = 0.f, im = 0.f;
    const float2* crow = COUT + (size_t)(pbase + c) * MM * MM + kx;
    #pragma unroll 8
    for (int j = 0; j < MM; ++j) {
        float2 w = crow[j * MM];
        float2 t = tab[j * Ny + y];
        re += w.x*t.x - w.y*t.y;
        im += w.x*t.y + w.y*t.x;
    }
    D[(size_t)(c*Ny + y)*MM + kx] = make_float2(re, im);
}

// ---------------- inverse DFT along x (c2r): D(r,kx) -> S(r,x) ----------------
__global__ __launch_bounds__(256) void k_inv_x(
        const float2* DA, const float2* DB, float* SA, float* SB,
        const float* tixA, const float* tixB) {
    __shared__ float2 ds[256];
    int bid = blockIdx.x;
    const int NBA = PA*HA/4;  // 3072
    if (bid < NBA) {
        int r0 = bid * 4;
        if (threadIdx.x < 128) {
            int q = threadIdx.x >> 5, kx = threadIdx.x & 31;
            ds[q*32+kx] = DA[(size_t)(r0+q)*MM + kx];
        }
        __syncthreads();
        int x = threadIdx.x;
        const float2* tab = (const float2*)tixA;
        float a0=0,a1=0,a2=0,a3=0;
        for (int kx = 0; kx < MM; ++kx) {
            float2 t = tab[kx*WA + x];
            float2 d0 = ds[kx], d1 = ds[32+kx], d2 = ds[64+kx], d3 = ds[96+kx];
            a0 += d0.x*t.x - d0.y*t.y;
            a1 += d1.x*t.x - d1.y*t.y;
            a2 += d2.x*t.x - d2.y*t.y;
            a3 += d3.x*t.x - d3.y*t.y;
        }
        SA[(size_t)(r0+0)*WA + x] = a0;
        SA[(size_t)(r0+1)*WA + x] = a1;
        SA[(size_t)(r0+2)*WA + x] = a2;
        SA[(size_t)(r0+3)*WA + x] = a3;
    } else {
        bid -= NBA;
        int r0 = bid * 8;
        { int q = threadIdx.x >> 5, kx = threadIdx.x & 31;
          ds[q*32+kx] = DB[(size_t)(r0+q)*MM + kx]; }
        __syncthreads();
        int x = threadIdx.x & 127;
        int h = threadIdx.x >> 7;
        int base = h*4*32;
        const float2* tab = (const float2*)tixB;
        float a0=0,a1=0,a2=0,a3=0;
        for (int kx = 0; kx < MM; ++kx) {
            float2 t = tab[kx*WB + x];
            float2 d0 = ds[base+kx], d1 = ds[base+32+kx], d2 = ds[base+64+kx], d3 = ds[base+96+kx];
            a0 += d0.x*t.x - d0.y*t.y;
            a1 += d1.x*t.x - d1.y*t.y;
            a2 += d2.x*t.x - d2.y*t.y;
            a3 += d3.x*t.x - d3.y*t.y;
        }
        SB[(size_t)(r0+h*4+0)*WB + x] = a0;
        SB[(size_t)(r0+h*4+1)*WB + x] = a1;
        SB[(size_t)(r0+h*4+2)*WB + x] = a2;
        SB[(size_t)(r0+h*4+3)*WB + x] = a3;
    }
}

// ---------------- A-branch 1x1 conv 48->48 + gelu (+resid) ----------------
// grid (128, 3): 512 px per block, o-group of 16; thread: 2 px x 16 o
__global__ __launch_bounds__(256) void k_conv1x1(
        const float* in, float* out, const float* w, const float* b,
        const float* resid) {
    __shared__ __attribute__((aligned(16))) float wl[PA*16];
    __shared__ float bl[16];
    int o0 = blockIdx.y * 16;
    for (int idx = threadIdx.x; idx < PA*16; idx += 256) {
        int oo = idx & 15, ii = idx >> 4;
        wl[idx] = w[(o0+oo)*PA + ii];
    }
    if (threadIdx.x < 16) bl[threadIdx.x] = b[o0+threadIdx.x];
    __syncthreads();
    int pix0 = (blockIdx.x*256 + threadIdx.x)*2;
    float acc[16][2];
    #pragma unroll
    for (int oo = 0; oo < 16; ++oo) { acc[oo][0]=bl[oo]; acc[oo][1]=bl[oo]; }
    for (int i = 0; i < PA; ++i) {
        float2 s = *(const float2*)(in + (size_t)i*NPIXA + pix0);
        const float4* wv = (const float4*)(wl + i*16);
        float wq[16];
        *(float4*)(wq+0)  = wv[0];
        *(float4*)(wq+4)  = wv[1];
        *(float4*)(wq+8)  = wv[2];
        *(float4*)(wq+12) = wv[3];
        #pragma unroll
        for (int oo = 0; oo < 16; ++oo) {
            acc[oo][0] += wq[oo]*s.x;
            acc[oo][1] += wq[oo]*s.y;
        }
    }
    #pragma unroll
    for (int oo = 0; oo < 16; ++oo) {
        size_t obase = (size_t)(o0+oo)*NPIXA + pix0;
        float2 r;
        r.x = gelu_f(acc[oo][0]);
        r.y = gelu_f(acc[oo][1]);
        if (resid) { float2 rv = *(const float2*)(resid+obase); r.x += rv.x; r.y += rv.y; }
        *(float2*)(out+obase) = r;
    }
}

// ---------------- B-branch 3x3 conv 48->48 + gelu (+resid), SAME pad ----------------
// grid (32, 4): 4 rows per block, o-group of 12; thread: 2 px x 12 o
__global__ __launch_bounds__(256) void k_conv3x3(
        const float* in, float* out, const float* w, const float* b,
        const float* resid) {
    __shared__ __attribute__((aligned(16))) float wl[9*PB*12];  // [k][i][oo]
    __shared__ float tile[6*130];
    __shared__ float bl[12];
    int o0 = blockIdx.y * 12;
    for (int idx = threadIdx.x; idx < 9*PB*12; idx += 256) {
        int oo = idx % 12;
        int rest = idx / 12;
        int i = rest % PB;
        int k = rest / PB;
        wl[idx] = w[((size_t)(o0+oo)*PB + i)*9 + k];
    }
    if (threadIdx.x < 12) bl[threadIdx.x] = b[o0+threadIdx.x];
    __syncthreads();
    int y0 = blockIdx.x * 4;
    int row = threadIdx.x >> 6;          // 0..3
    int x0 = (threadIdx.x & 63) * 2;     // 0..126
    float acc[12][2];
    #pragma unroll
    for (int oo = 0; oo < 12; ++oo) { acc[oo][0] = bl[oo]; acc[oo][1] = bl[oo]; }
    for (int i = 0; i < PB; ++i) {
        __syncthreads();
        const float* ip = in + (size_t)i*NPIXB;
        for (int idx = threadIdx.x; idx < 6*130; idx += 256) {
            int r = idx / 130, cc = idx - r*130;
            int gy = y0 + r - 1, gx = cc - 1;
            tile[idx] = (gy >= 0 && gy < HB && gx >= 0 && gx < WB) ? ip[gy*WB+gx] : 0.f;
        }
        __syncthreads();
        #pragma unroll
        for (int dy = 0; dy < 3; ++dy) {
            float sv0 = tile[(row+dy)*130 + x0 + 0];
            float sv1 = tile[(row+dy)*130 + x0 + 1];
            float sv2 = tile[(row+dy)*130 + x0 + 2];
            float sv3 = tile[(row+dy)*130 + x0 + 3];
            #pragma unroll
            for (int dx = 0; dx < 3; ++dx) {
                const float4* wv = (const float4*)(wl + ((dy*3+dx)*PB + i)*12);
                float wq[12];
                *(float4*)(wq+0) = wv[0];
                *(float4*)(wq+4) = wv[1];
                *(float4*)(wq+8) = wv[2];
                float s0 = (dx==0)?sv0:((dx==1)?sv1:sv2);
                float s1 = (dx==0)?sv1:((dx==1)?sv2:sv3);
                #pragma unroll
                for (int oo = 0; oo < 12; ++oo) {
                    acc[oo][0] += wq[oo]*s0;
                    acc[oo][1] += wq[oo]*s1;
                }
            }
        }
    }
    int gy = y0 + row;
    #pragma unroll
    for (int oo = 0; oo < 12; ++oo) {
        size_t obase = (size_t)(o0+oo)*NPIXB + (size_t)gy*WB + x0;
        float2 r;
        r.x = gelu_f(acc[oo][0]);
        r.y = gelu_f(acc[oo][1]);
        if (resid) { float2 rv = *(const float2*)(resid+obase); r.x += rv.x; r.y += rv.y; }
        *(float2*)(out+obase) = r;
    }
}

// ---------------- decoder: 48->1 both branches ----------------
__global__ __launch_bounds__(256) void k_decode(
        const float* UA, const float* UB, const float* dwa, const float* dba,
        const float* dwb, const float* dbb, float* outp) {
    int t = blockIdx.x*256 + threadIdx.x;
    if (t < NPIXA) {
        float acc = dba[0];
        #pragma unroll 8
        for (int p = 0; p < PA; ++p) acc += dwa[p]*UA[(size_t)p*NPIXA + t];
        outp[t] = acc;
    } else {
        int u = t - NPIXA;
        float acc = dbb[0];
        #pragma unroll 8
        for (int p = 0; p < PB; ++p) acc += dwb[p]*UB[(size_t)p*NPIXB + u];
        outp[t] = acc;
    }
}

extern "C" void kernel_launch(void* const* d_in, const int* in_sizes, int n_in,
                              void* d_out, int out_size, void* d_ws, size_t ws_size,
                              hipStream_t stream) {
    const float* u_a   = (const float*)d_in[0];
    const float* x_a   = (const float*)d_in[1];
    const float* u_b   = (const float*)d_in[2];
    const float* x_b   = (const float*)d_in[3];
    const float* enc_a_w = (const float*)d_in[4];
    const float* enc_a_b = (const float*)d_in[5];
    const float* enc_b_w = (const float*)d_in[6];
    const float* enc_b_b = (const float*)d_in[7];
    const float* dec_a_w = (const float*)d_in[8];
    const float* dec_a_b = (const float*)d_in[9];
    const float* dec_b_w = (const float*)d_in[10];
    const float* dec_b_b = (const float*)d_in[11];
    const float* c1a_w = (const float*)d_in[12];
    const float* c1a_b = (const float*)d_in[13];
    const float* c2a_w = (const float*)d_in[14];
    const float* c2a_b = (const float*)d_in[15];
    const float* c1b_w = (const float*)d_in[16];
    const float* c1b_b = (const float*)d_in[17];
    const float* c2b_w = (const float*)d_in[18];
    const float* c2b_b = (const float*)d_in[19];
    const float* A_re = (const float*)d_in[20];
    const float* A_im = (const float*)d_in[21];

    float* ws = (float*)d_ws;
    size_t off = 0;
    auto alloc = [&](size_t n) { float* p = ws + off; off += n; return p; };
    float* TfxA = alloc(MM*WA*2);
    float* TfyA = alloc(MM*HA*2);
    float* TixA = alloc(MM*WA*2);
    float* TiyA = alloc(MM*HA*2);
    float* TfxB = alloc(MM*WB*2);
    float* TfyB = alloc(MM*HB*2);
    float* TixB = alloc(MM*WB*2);
    float* TiyB = alloc(MM*HB*2);
    float* UA = alloc((size_t)PA*NPIXA);
    float* UB = alloc((size_t)PB*NPIXB);
    float* SA = alloc((size_t)PA*NPIXA);
    float* TA = alloc((size_t)PA*NPIXA);
    float* SB = alloc((size_t)PB*NPIXB);
    float* TB = alloc((size_t)PB*NPIXB);
    float2* FA = (float2*)alloc((size_t)PA*HA*MM*2);
    float2* FB = (float2*)alloc((size_t)PB*HB*MM*2);
    float2* CIN  = (float2*)alloc((size_t)PP*MM*MM*2);
    float2* COUT = (float2*)alloc((size_t)PP*MM*MM*2);
    if (off * sizeof(float) > ws_size) return;  // workspace too small (would corrupt)

    k_gen_tables<<<dim3(48), dim3(256), 0, stream>>>(TfxA,TfyA,TixA,TiyA,TfxB,TfyB,TixB,TiyB);
    k_encode<<<dim3(320,48), dim3(256), 0, stream>>>(u_a,x_a,u_b,x_b,
        enc_a_w,enc_a_b,enc_b_w,enc_b_b, UA,UB);
    for (int l = 0; l < 4; ++l) {
        k_fwd_x<<<dim3(576), dim3(256), 32768, stream>>>(UA,UB,FA,FB,TfxA,TfxB);
        k_fwd_y<<<dim3(384), dim3(256), 0, stream>>>(FA,FB,CIN,TfyA,TfyB);
        k_spectral<<<dim3(384), dim3(256), 0, stream>>>(
            A_re + (size_t)l*PP*PP*MM*MM, A_im + (size_t)l*PP*PP*MM*MM, CIN, COUT);
        k_inv_y<<<dim3(2304), dim3(256), 0, stream>>>(COUT, FA, FB, TiyA, TiyB);
        k_inv_x<<<dim3(3840), dim3(256), 0, stream>>>(FA, FB, SA, SB, TixA, TixB);
        k_conv1x1<<<dim3(128,3), dim3(256), 0, stream>>>(SA, TA,
            c1a_w + (size_t)l*PA*PA, c1a_b + (size_t)l*PA, (const float*)nullptr);
        k_conv1x1<<<dim3(128,3), dim3(256), 0, stream>>>(TA, UA,
            c2a_w + (size_t)l*PA*PA, c2a_b + (size_t)l*PA, UA);
        k_conv3x3<<<dim3(32,4), dim3(256), 0, stream>>>(SB, TB,
            c1b_w + (size_t)l*PB*PB*9, c1b_b + (size_t)l*PB, (const float*)nullptr);
        k_conv3x3<<<dim3(32,4), dim3(256), 0, stream>>>(TB, UB,
            c2b_w + (size_t)l*PB*PB*9, c2b_b + (size_t)l*PB, UB);
    }
    k_decode<<<dim3(320), dim3(256), 0, stream>>>(UA, UB,
        dec_a_w, dec_a_b, dec_b_w, dec_b_b, (float*)d_out);
}

// Round 2
// 1030.491 us; speedup vs baseline: 1.2894x; 1.2894x over previous
//
#include <hip/hip_runtime.h>

#define HA 256
#define WA 256
#define HB 128
#define WB 128
#define PA 48
#define PB 48
#define PP 96
#define MM 32
#define NPIXA (HA*WA)   // 65536
#define NPIXB (HB*WB)   // 16384

__device__ __forceinline__ float gelu_f(float x) {
    float z = 0.7978845608028654f * (x + 0.044715f * x * x * x);
    float e = __expf(2.0f * z);
    return x - x / (e + 1.0f);
}

// ---------------- DFT twiddle tables ----------------
__global__ __launch_bounds__(256) void k_gen_tables(
        float* tfxA, float* tfyA, float* tixA, float* tiyA,
        float* tfxB, float* tfyB, float* tixB, float* tiyB) {
    const float TWO_PI = 6.28318530717958647692f;
    int t = blockIdx.x * 256 + threadIdx.x;
    if (t < MM * WA) {
        int k = t / WA, x = t - k * WA;
        int m = (k * x) & (WA - 1);
        float ang = TWO_PI * (float)m / (float)WA;
        float s, c; __sincosf(ang, &s, &c);
        float sc = 1.0f / (float)(HA * WA);
        tfxA[2*t] = c * sc; tfxA[2*t+1] = -s * sc;
        float wgt = (k == 0) ? 1.0f : 2.0f;
        tixA[2*t] = wgt * c; tixA[2*t+1] = wgt * s;
        int ky = k - 16;
        int my = (ky * x) & (HA - 1);
        float angy = TWO_PI * (float)my / (float)HA;
        float sy, cy; __sincosf(angy, &sy, &cy);
        tfyA[2*t] = cy; tfyA[2*t+1] = -sy;
        tiyA[2*t] = cy; tiyA[2*t+1] = sy;
    } else if (t < MM * WA + MM * WB) {
        int t2 = t - MM * WA;
        int k = t2 / WB, x = t2 - k * WB;
        int m = (k * x) & (WB - 1);
        float ang = TWO_PI * (float)m / (float)WB;
        float s, c; __sincosf(ang, &s, &c);
        float sc = 1.0f / (float)(HB * WB);
        tfxB[2*t2] = c * sc; tfxB[2*t2+1] = -s * sc;
        float wgt = (k == 0) ? 1.0f : 2.0f;
        tixB[2*t2] = wgt * c; tixB[2*t2+1] = wgt * s;
        int ky = k - 16;
        int my = (ky * x) & (HB - 1);
        float angy = TWO_PI * (float)my / (float)HB;
        float sy, cy; __sincosf(angy, &sy, &cy);
        tfyB[2*t2] = cy; tfyB[2*t2+1] = -sy;
        tiyB[2*t2] = cy; tiyB[2*t2+1] = sy;
    }
}

// ---------------- encoder (1x1 conv, 3->48) ----------------
__global__ __launch_bounds__(256) void k_encode(
        const float* u_a, const float* x_a, const float* u_b, const float* x_b,
        const float* wa, const float* ba, const float* wb, const float* bb,
        float* UA, float* UB) {
    int o = blockIdx.y;
    if (blockIdx.x < NPIXA/256) {
        int pix = blockIdx.x * 256 + threadIdx.x;
        UA[(size_t)o*NPIXA + pix] = wa[o*3+0]*x_a[pix] + wa[o*3+1]*x_a[NPIXA+pix]
                                  + wa[o*3+2]*u_a[pix] + ba[o];
    } else {
        int pix = (blockIdx.x - NPIXA/256) * 256 + threadIdx.x;
        UB[(size_t)o*NPIXB + pix] = wb[o*3+0]*x_b[pix] + wb[o*3+1]*x_b[NPIXB+pix]
                                  + wb[o*3+2]*u_b[pix] + bb[o];
    }
}

// ---------------- forward DFT along x ----------------
__global__ __launch_bounds__(256) void k_fwd_x(
        const float* UA, const float* UB, float2* FA, float2* FB,
        const float* tfxA, const float* tfxB) {
    extern __shared__ float ls[];
    int bid = blockIdx.x;
    const float* U; float2* F; const float2* tab; int N;
    const int NBA = PA * HA / 32;   // 384
    if (bid < NBA) { U = UA; F = FA; tab = (const float2*)tfxA; N = WA; }
    else { bid -= NBA; U = UB; F = FB; tab = (const float2*)tfxB; N = WB; }
    int r0 = bid * 32;
    int tot4 = 32 * N / 4;
    const float4* src = (const float4*)(U + (size_t)r0 * N);
    for (int i = threadIdx.x; i < tot4; i += 256) ((float4*)ls)[i] = src[i];
    __syncthreads();
    int kx = threadIdx.x & 31;
    int rg = (threadIdx.x >> 5) * 4;
    float ar0=0,ai0=0,ar1=0,ai1=0,ar2=0,ai2=0,ar3=0,ai3=0;
    const float2* tk = tab + kx * N;
    for (int x = 0; x < N; ++x) {
        float2 t = tk[x];
        float u0 = ls[(rg+0)*N + x];
        float u1 = ls[(rg+1)*N + x];
        float u2 = ls[(rg+2)*N + x];
        float u3 = ls[(rg+3)*N + x];
        ar0 += u0*t.x; ai0 += u0*t.y;
        ar1 += u1*t.x; ai1 += u1*t.y;
        ar2 += u2*t.x; ai2 += u2*t.y;
        ar3 += u3*t.x; ai3 += u3*t.y;
    }
    F[(size_t)(r0+rg+0)*MM + kx] = make_float2(ar0, ai0);
    F[(size_t)(r0+rg+1)*MM + kx] = make_float2(ar1, ai1);
    F[(size_t)(r0+rg+2)*MM + kx] = make_float2(ar2, ai2);
    F[(size_t)(r0+rg+3)*MM + kx] = make_float2(ar3, ai3);
}

// ---------------- forward DFT along y ----------------
__global__ __launch_bounds__(256) void k_fwd_y(
        const float2* FA, const float2* FB, float2* CIN,
        const float* tfyA, const float* tfyB) {
    int bid = blockIdx.x;
    const float2* F; const float2* tab; int Ny, pbase;
    if (bid < PA*4) { F = FA; tab = (const float2*)tfyA; Ny = HA; pbase = 0; }
    else { bid -= PA*4; F = FB; tab = (const float2*)tfyB; Ny = HB; pbase = PA; }
    int c = bid >> 2;
    int j = (bid & 3) * 8 + (threadIdx.x >> 5);
    int kx = threadIdx.x & 31;
    float re = 0.f, im = 0.f;
    const float2* fr = F + (size_t)c * Ny * MM + kx;
    const float2* tj = tab + j * Ny;
    #pragma unroll 4
    for (int y = 0; y < Ny; ++y) {
        float2 f = fr[y * MM];
        float2 t = tj[y];
        re += f.x*t.x - f.y*t.y;
        im += f.x*t.y + f.y*t.x;
    }
    CIN[((pbase + c)*MM + j)*MM + kx] = make_float2(re, im);
}

// ---------------- spectral channel mix ----------------
__global__ __launch_bounds__(256) void k_spectral(
        const float* Wre, const float* Wim, const float2* CIN, float2* COUT) {
    int t = blockIdx.x * 256 + threadIdx.x;
    int p = t >> 10;
    int mode = t & 1023;
    const float* wr = Wre + (size_t)p * PP * 1024 + mode;
    const float* wi = Wim + (size_t)p * PP * 1024 + mode;
    float re = 0.f, im = 0.f;
    #pragma unroll 4
    for (int q = 0; q < PP; ++q) {
        float a = wr[(size_t)q * 1024];
        float b = wi[(size_t)q * 1024];
        float2 cv = CIN[q * 1024 + mode];
        re += a*cv.x - b*cv.y;
        im += a*cv.y + b*cv.x;
    }
    COUT[p * 1024 + mode] = make_float2(re, im);
}

// ---------------- inverse DFT along y ----------------
__global__ __launch_bounds__(256) void k_inv_y(
        const float2* COUT, float2* DA, float2* DB,
        const float* tiyA, const float* tiyB) {
    int bid = blockIdx.x;
    float2* D; const float2* tab; int Ny, pbase, c, yg;
    if (bid < PA*(HA/8)) { D = DA; tab = (const float2*)tiyA; Ny = HA; pbase = 0;
        c = bid >> 5; yg = bid & 31; }
    else { bid -= PA*(HA/8); D = DB; tab = (const float2*)tiyB; Ny = HB; pbase = PA;
        c = bid >> 4; yg = bid & 15; }
    int kx = threadIdx.x & 31;
    int y = yg * 8 + (threadIdx.x >> 5);
    float re = 0.f, im = 0.f;
    const float2* crow = COUT + (size_t)(pbase + c) * MM * MM + kx;
    #pragma unroll 8
    for (int j = 0; j < MM; ++j) {
        float2 w = crow[j * MM];
        float2 t = tab[j * Ny + y];
        re += w.x*t.x - w.y*t.y;
        im += w.x*t.y + w.y*t.x;
    }
    D[(size_t)(c*Ny + y)*MM + kx] = make_float2(re, im);
}

// ---------------- inverse DFT along x (c2r) ----------------
__global__ __launch_bounds__(256) void k_inv_x(
        const float2* DA, const float2* DB, float* SA, float* SB,
        const float* tixA, const float* tixB) {
    __shared__ float2 ds[256];
    int bid = blockIdx.x;
    const int NBA = PA*HA/4;  // 3072
    if (bid < NBA) {
        int r0 = bid * 4;
        if (threadIdx.x < 128) {
            int q = threadIdx.x >> 5, kx = threadIdx.x & 31;
            ds[q*32+kx] = DA[(size_t)(r0+q)*MM + kx];
        }
        __syncthreads();
        int x = threadIdx.x;
        const float2* tab = (const float2*)tixA;
        float a0=0,a1=0,a2=0,a3=0;
        for (int kx = 0; kx < MM; ++kx) {
            float2 t = tab[kx*WA + x];
            float2 d0 = ds[kx], d1 = ds[32+kx], d2 = ds[64+kx], d3 = ds[96+kx];
            a0 += d0.x*t.x - d0.y*t.y;
            a1 += d1.x*t.x - d1.y*t.y;
            a2 += d2.x*t.x - d2.y*t.y;
            a3 += d3.x*t.x - d3.y*t.y;
        }
        SA[(size_t)(r0+0)*WA + x] = a0;
        SA[(size_t)(r0+1)*WA + x] = a1;
        SA[(size_t)(r0+2)*WA + x] = a2;
        SA[(size_t)(r0+3)*WA + x] = a3;
    } else {
        bid -= NBA;
        int r0 = bid * 8;
        { int q = threadIdx.x >> 5, kx = threadIdx.x & 31;
          ds[q*32+kx] = DB[(size_t)(r0+q)*MM + kx]; }
        __syncthreads();
        int x = threadIdx.x & 127;
        int h = threadIdx.x >> 7;
        int base = h*4*32;
        const float2* tab = (const float2*)tixB;
        float a0=0,a1=0,a2=0,a3=0;
        for (int kx = 0; kx < MM; ++kx) {
            float2 t = tab[kx*WB + x];
            float2 d0 = ds[base+kx], d1 = ds[base+32+kx], d2 = ds[base+64+kx], d3 = ds[base+96+kx];
            a0 += d0.x*t.x - d0.y*t.y;
            a1 += d1.x*t.x - d1.y*t.y;
            a2 += d2.x*t.x - d2.y*t.y;
            a3 += d3.x*t.x - d3.y*t.y;
        }
        SB[(size_t)(r0+h*4+0)*WB + x] = a0;
        SB[(size_t)(r0+h*4+1)*WB + x] = a1;
        SB[(size_t)(r0+h*4+2)*WB + x] = a2;
        SB[(size_t)(r0+h*4+3)*WB + x] = a3;
    }
}

// ---------------- A-branch 1x1 conv 48->48 + gelu (+resid) ----------------
// grid (128, 6): 512 px per block, o-group of 8; thread: 2 px x 8 o
__global__ __launch_bounds__(256) void k_conv1x1(
        const float* in, float* out, const float* w, const float* b,
        const float* resid) {
    __shared__ __attribute__((aligned(16))) float wl[PA*8];
    __shared__ float bl[8];
    int o0 = blockIdx.y * 8;
    for (int idx = threadIdx.x; idx < PA*8; idx += 256) {
        int oo = idx & 7, ii = idx >> 3;
        wl[idx] = w[(o0+oo)*PA + ii];
    }
    if (threadIdx.x < 8) bl[threadIdx.x] = b[o0+threadIdx.x];
    __syncthreads();
    int pix0 = (blockIdx.x*256 + threadIdx.x)*2;
    float acc[8][2];
    #pragma unroll
    for (int oo = 0; oo < 8; ++oo) { acc[oo][0]=bl[oo]; acc[oo][1]=bl[oo]; }
    for (int i = 0; i < PA; ++i) {
        float2 s = *(const float2*)(in + (size_t)i*NPIXA + pix0);
        const float4* wv = (const float4*)(wl + i*8);
        float wq[8];
        *(float4*)(wq+0) = wv[0];
        *(float4*)(wq+4) = wv[1];
        #pragma unroll
        for (int oo = 0; oo < 8; ++oo) {
            acc[oo][0] += wq[oo]*s.x;
            acc[oo][1] += wq[oo]*s.y;
        }
    }
    #pragma unroll
    for (int oo = 0; oo < 8; ++oo) {
        size_t obase = (size_t)(o0+oo)*NPIXA + pix0;
        float2 r;
        r.x = gelu_f(acc[oo][0]);
        r.y = gelu_f(acc[oo][1]);
        if (resid) { float2 rv = *(const float2*)(resid+obase); r.x += rv.x; r.y += rv.y; }
        *(float2*)(out+obase) = r;
    }
}

// ---------------- B-branch 3x3 conv 48->48 + gelu (+resid), SAME pad ----------------
// Barrier-free channel loop: 1 wave = 1 output row (64 lanes x 2px = 128 cols),
// halo via shuffles, weights staged once in LDS [ic][tap][oc pad 8], broadcast reads.
// grid (32, 8): block = 4 rows x 6 output channels.
__global__ __launch_bounds__(256) void k_conv3x3(
        const float* in, float* out, const float* w, const float* b,
        const float* resid) {
    __shared__ __attribute__((aligned(16))) float wl[PB*9*8];  // [ic][tap][oo(6,pad8)]
    __shared__ float bl[6];
    int o0 = blockIdx.y * 6;
    for (int idx = threadIdx.x; idx < PB*9*6; idx += 256) {
        int oo = idx % 6;
        int r = idx / 6;
        int tap = r % 9;
        int ic = r / 9;
        wl[(ic*9+tap)*8 + oo] = w[((size_t)(o0+oo)*PB + ic)*9 + tap];
    }
    if (threadIdx.x < 6) bl[threadIdx.x] = b[o0+threadIdx.x];
    __syncthreads();

    int wv = threadIdx.x >> 6;           // wave id 0..3
    int lane = threadIdx.x & 63;
    int y = blockIdx.x * 4 + wv;         // output row
    int x0 = lane * 2;

    float acc[6][2];
    #pragma unroll
    for (int oo = 0; oo < 6; ++oo) { acc[oo][0]=bl[oo]; acc[oo][1]=bl[oo]; }

    for (int ic = 0; ic < PB; ++ic) {
        const float* ip = in + (size_t)ic*NPIXB;
        // window per dy: [lft, s.x, s.y, rgt] = x0-1, x0, x0+1, x0+2
        float win[3][4];
        #pragma unroll
        for (int dy = 0; dy < 3; ++dy) {
            int gy = y - 1 + dy;
            float2 s;
            if (gy >= 0 && gy < HB) s = *(const float2*)(ip + gy*WB + x0);
            else { s.x = 0.f; s.y = 0.f; }
            float lft = __shfl_up(s.y, 1);
            if (lane == 0) lft = 0.f;
            float rgt = __shfl_down(s.x, 1);
            if (lane == 63) rgt = 0.f;
            win[dy][0] = lft; win[dy][1] = s.x; win[dy][2] = s.y; win[dy][3] = rgt;
        }
        const float* wb_ = wl + ic*9*8;
        #pragma unroll
        for (int tap = 0; tap < 9; ++tap) {
            int dy = tap / 3, dx = tap % 3;
            float4 w03 = *(const float4*)(wb_ + tap*8);
            float2 w45 = *(const float2*)(wb_ + tap*8 + 4);
            float s0 = win[dy][dx];
            float s1 = win[dy][dx+1];
            acc[0][0] += w03.x*s0; acc[0][1] += w03.x*s1;
            acc[1][0] += w03.y*s0; acc[1][1] += w03.y*s1;
            acc[2][0] += w03.z*s0; acc[2][1] += w03.z*s1;
            acc[3][0] += w03.w*s0; acc[3][1] += w03.w*s1;
            acc[4][0] += w45.x*s0; acc[4][1] += w45.x*s1;
            acc[5][0] += w45.y*s0; acc[5][1] += w45.y*s1;
        }
    }
    #pragma unroll
    for (int oo = 0; oo < 6; ++oo) {
        size_t obase = (size_t)(o0+oo)*NPIXB + (size_t)y*WB + x0;
        float2 r;
        r.x = gelu_f(acc[oo][0]);
        r.y = gelu_f(acc[oo][1]);
        if (resid) { float2 rv = *(const float2*)(resid+obase); r.x += rv.x; r.y += rv.y; }
        *(float2*)(out+obase) = r;
    }
}

// ---------------- decoder: 48->1 both branches ----------------
__global__ __launch_bounds__(256) void k_decode(
        const float* UA, const float* UB, const float* dwa, const float* dba,
        const float* dwb, const float* dbb, float* outp) {
    int t = blockIdx.x*256 + threadIdx.x;
    if (t < NPIXA) {
        float acc = dba[0];
        #pragma unroll 8
        for (int p = 0; p < PA; ++p) acc += dwa[p]*UA[(size_t)p*NPIXA + t];
        outp[t] = acc;
    } else {
        int u = t - NPIXA;
        float acc = dbb[0];
        #pragma unroll 8
        for (int p = 0; p < PB; ++p) acc += dwb[p]*UB[(size_t)p*NPIXB + u];
        outp[t] = acc;
    }
}

extern "C" void kernel_launch(void* const* d_in, const int* in_sizes, int n_in,
                              void* d_out, int out_size, void* d_ws, size_t ws_size,
                              hipStream_t stream) {
    const float* u_a   = (const float*)d_in[0];
    const float* x_a   = (const float*)d_in[1];
    const float* u_b   = (const float*)d_in[2];
    const float* x_b   = (const float*)d_in[3];
    const float* enc_a_w = (const float*)d_in[4];
    const float* enc_a_b = (const float*)d_in[5];
    const float* enc_b_w = (const float*)d_in[6];
    const float* enc_b_b = (const float*)d_in[7];
    const float* dec_a_w = (const float*)d_in[8];
    const float* dec_a_b = (const float*)d_in[9];
    const float* dec_b_w = (const float*)d_in[10];
    const float* dec_b_b = (const float*)d_in[11];
    const float* c1a_w = (const float*)d_in[12];
    const float* c1a_b = (const float*)d_in[13];
    const float* c2a_w = (const float*)d_in[14];
    const float* c2a_b = (const float*)d_in[15];
    const float* c1b_w = (const float*)d_in[16];
    const float* c1b_b = (const float*)d_in[17];
    const float* c2b_w = (const float*)d_in[18];
    const float* c2b_b = (const float*)d_in[19];
    const float* A_re = (const float*)d_in[20];
    const float* A_im = (const float*)d_in[21];

    float* ws = (float*)d_ws;
    size_t off = 0;
    auto alloc = [&](size_t n) { float* p = ws + off; off += n; return p; };
    float* TfxA = alloc(MM*WA*2);
    float* TfyA = alloc(MM*HA*2);
    float* TixA = alloc(MM*WA*2);
    float* TiyA = alloc(MM*HA*2);
    float* TfxB = alloc(MM*WB*2);
    float* TfyB = alloc(MM*HB*2);
    float* TixB = alloc(MM*WB*2);
    float* TiyB = alloc(MM*HB*2);
    float* UA = alloc((size_t)PA*NPIXA);
    float* UB = alloc((size_t)PB*NPIXB);
    float* SA = alloc((size_t)PA*NPIXA);
    float* TA = alloc((size_t)PA*NPIXA);
    float* SB = alloc((size_t)PB*NPIXB);
    float* TB = alloc((size_t)PB*NPIXB);
    float2* FA = (float2*)alloc((size_t)PA*HA*MM*2);
    float2* FB = (float2*)alloc((size_t)PB*HB*MM*2);
    float2* CIN  = (float2*)alloc((size_t)PP*MM*MM*2);
    float2* COUT = (float2*)alloc((size_t)PP*MM*MM*2);
    if (off * sizeof(float) > ws_size) return;

    k_gen_tables<<<dim3(48), dim3(256), 0, stream>>>(TfxA,TfyA,TixA,TiyA,TfxB,TfyB,TixB,TiyB);
    k_encode<<<dim3(320,48), dim3(256), 0, stream>>>(u_a,x_a,u_b,x_b,
        enc_a_w,enc_a_b,enc_b_w,enc_b_b, UA,UB);
    for (int l = 0; l < 4; ++l) {
        k_fwd_x<<<dim3(576), dim3(256), 32768, stream>>>(UA,UB,FA,FB,TfxA,TfxB);
        k_fwd_y<<<dim3(384), dim3(256), 0, stream>>>(FA,FB,CIN,TfyA,TfyB);
        k_spectral<<<dim3(384), dim3(256), 0, stream>>>(
            A_re + (size_t)l*PP*PP*MM*MM, A_im + (size_t)l*PP*PP*MM*MM, CIN, COUT);
        k_inv_y<<<dim3(2304), dim3(256), 0, stream>>>(COUT, FA, FB, TiyA, TiyB);
        k_inv_x<<<dim3(3840), dim3(256), 0, stream>>>(FA, FB, SA, SB, TixA, TixB);
        k_conv1x1<<<dim3(128,6), dim3(256), 0, stream>>>(SA, TA,
            c1a_w + (size_t)l*PA*PA, c1a_b + (size_t)l*PA, (const float*)nullptr);
        k_conv1x1<<<dim3(128,6), dim3(256), 0, stream>>>(TA, UA,
            c2a_w + (size_t)l*PA*PA, c2a_b + (size_t)l*PA, UA);
        k_conv3x3<<<dim3(32,8), dim3(256), 0, stream>>>(SB, TB,
            c1b_w + (size_t)l*PB*PB*9, c1b_b + (size_t)l*PB, (const float*)nullptr);
        k_conv3x3<<<dim3(32,8), dim3(256), 0, stream>>>(TB, UB,
            c2b_w + (size_t)l*PB*PB*9, c2b_b + (size_t)l*PB, UB);
    }
    k_decode<<<dim3(320), dim3(256), 0, stream>>>(UA, UB,
        dec_a_w, dec_a_b, dec_b_w, dec_b_b, (float*)d_out);
}

// Round 3
// 740.576 us; speedup vs baseline: 1.7942x; 1.3915x over previous
//
#include <hip/hip_runtime.h>

#define HA 256
#define WA 256
#define HB 128
#define WB 128
#define PA 48
#define PB 48
#define PP 96
#define MM 32
#define NPIXA (HA*WA)   // 65536
#define NPIXB (HB*WB)   // 16384

__device__ __forceinline__ float gelu_f(float x) {
    float z = 0.7978845608028654f * (x + 0.044715f * x * x * x);
    float e = __expf(2.0f * z);
    return x - x / (e + 1.0f);
}

// ---------------- DFT twiddle tables ----------------
// plain layout [k][x] (used by fwd_y/inv_y/inv_xb), transposed [x][k] for fwd_x.
__global__ __launch_bounds__(256) void k_gen_tables(
        float* tfxAT, float* tfyA, float* tixA, float* tiyA,
        float* tfxBT, float* tfyB, float* tixB, float* tiyB) {
    const float TWO_PI = 6.28318530717958647692f;
    int t = blockIdx.x * 256 + threadIdx.x;
    if (t < MM * WA) {
        int k = t / WA, x = t - k * WA;
        int m = (k * x) & (WA - 1);
        float ang = TWO_PI * (float)m / (float)WA;
        float s, c; __sincosf(ang, &s, &c);
        float sc = 1.0f / (float)(HA * WA);
        tfxAT[(x*MM + k)*2]   = c * sc;
        tfxAT[(x*MM + k)*2+1] = -s * sc;
        float wgt = (k == 0) ? 1.0f : 2.0f;
        tixA[2*t] = wgt * c; tixA[2*t+1] = wgt * s;
        int ky = k - 16;
        int my = (ky * x) & (HA - 1);
        float angy = TWO_PI * (float)my / (float)HA;
        float sy, cy; __sincosf(angy, &sy, &cy);
        tfyA[2*t] = cy; tfyA[2*t+1] = -sy;
        tiyA[2*t] = cy; tiyA[2*t+1] = sy;
    } else if (t < MM * WA + MM * WB) {
        int t2 = t - MM * WA;
        int k = t2 / WB, x = t2 - k * WB;
        int m = (k * x) & (WB - 1);
        float ang = TWO_PI * (float)m / (float)WB;
        float s, c; __sincosf(ang, &s, &c);
        float sc = 1.0f / (float)(HB * WB);
        tfxBT[(x*MM + k)*2]   = c * sc;
        tfxBT[(x*MM + k)*2+1] = -s * sc;
        float wgt = (k == 0) ? 1.0f : 2.0f;
        tixB[2*t2] = wgt * c; tixB[2*t2+1] = wgt * s;
        int ky = k - 16;
        int my = (ky * x) & (WB*HB/WB - 1);  // & (HB-1)
        float angy = TWO_PI * (float)my / (float)HB;
        float sy, cy; __sincosf(angy, &sy, &cy);
        tfyB[2*t2] = cy; tfyB[2*t2+1] = -sy;
        tiyB[2*t2] = cy; tiyB[2*t2+1] = sy;
    }
}

// ---------------- encoder (1x1 conv, 3->48) ----------------
__global__ __launch_bounds__(256) void k_encode(
        const float* u_a, const float* x_a, const float* u_b, const float* x_b,
        const float* wa, const float* ba, const float* wb, const float* bb,
        float* UA, float* UB) {
    int o = blockIdx.y;
    if (blockIdx.x < NPIXA/256) {
        int pix = blockIdx.x * 256 + threadIdx.x;
        UA[(size_t)o*NPIXA + pix] = wa[o*3+0]*x_a[pix] + wa[o*3+1]*x_a[NPIXA+pix]
                                  + wa[o*3+2]*u_a[pix] + ba[o];
    } else {
        int pix = (blockIdx.x - NPIXA/256) * 256 + threadIdx.x;
        UB[(size_t)o*NPIXB + pix] = wb[o*3+0]*x_b[pix] + wb[o*3+1]*x_b[NPIXB+pix]
                                  + wb[o*3+2]*u_b[pix] + bb[o];
    }
}

// ---------------- forward DFT along x (transposed twiddle table) ----------------
__global__ __launch_bounds__(256) void k_fwd_x(
        const float* __restrict__ UA, const float* __restrict__ UB,
        float2* __restrict__ FA, float2* __restrict__ FB,
        const float* __restrict__ tfxAT, const float* __restrict__ tfxBT) {
    extern __shared__ float ls[];
    int bid = blockIdx.x;
    const float* U; float2* F; const float2* tT; int N;
    const int NBA = PA * HA / 32;   // 384
    if (bid < NBA) { U = UA; F = FA; tT = (const float2*)tfxAT; N = WA; }
    else { bid -= NBA; U = UB; F = FB; tT = (const float2*)tfxBT; N = WB; }
    int r0 = bid * 32;
    int tot4 = 32 * N / 4;
    const float4* src = (const float4*)(U + (size_t)r0 * N);
    for (int i = threadIdx.x; i < tot4; i += 256) ((float4*)ls)[i] = src[i];
    __syncthreads();
    int kx = threadIdx.x & 31;
    int rg = (threadIdx.x >> 5) * 4;
    float ar0=0,ai0=0,ar1=0,ai1=0,ar2=0,ai2=0,ar3=0,ai3=0;
    for (int x = 0; x < N; ++x) {
        float2 t = tT[x*MM + kx];      // coalesced: lanes read consecutive kx
        float u0 = ls[(rg+0)*N + x];
        float u1 = ls[(rg+1)*N + x];
        float u2 = ls[(rg+2)*N + x];
        float u3 = ls[(rg+3)*N + x];
        ar0 += u0*t.x; ai0 += u0*t.y;
        ar1 += u1*t.x; ai1 += u1*t.y;
        ar2 += u2*t.x; ai2 += u2*t.y;
        ar3 += u3*t.x; ai3 += u3*t.y;
    }
    F[(size_t)(r0+rg+0)*MM + kx] = make_float2(ar0, ai0);
    F[(size_t)(r0+rg+1)*MM + kx] = make_float2(ar1, ai1);
    F[(size_t)(r0+rg+2)*MM + kx] = make_float2(ar2, ai2);
    F[(size_t)(r0+rg+3)*MM + kx] = make_float2(ar3, ai3);
}

// ---------------- forward DFT along y ----------------
__global__ __launch_bounds__(256) void k_fwd_y(
        const float2* __restrict__ FA, const float2* __restrict__ FB, float2* CIN,
        const float* __restrict__ tfyA, const float* __restrict__ tfyB) {
    int bid = blockIdx.x;
    const float2* F; const float2* tab; int Ny, pbase;
    if (bid < PA*4) { F = FA; tab = (const float2*)tfyA; Ny = HA; pbase = 0; }
    else { bid -= PA*4; F = FB; tab = (const float2*)tfyB; Ny = HB; pbase = PA; }
    int c = bid >> 2;
    int j = (bid & 3) * 8 + (threadIdx.x >> 5);
    int kx = threadIdx.x & 31;
    float re = 0.f, im = 0.f;
    const float2* fr = F + (size_t)c * Ny * MM + kx;
    const float2* tj = tab + j * Ny;
    #pragma unroll 4
    for (int y = 0; y < Ny; ++y) {
        float2 f = fr[y * MM];
        float2 t = tj[y];
        re += f.x*t.x - f.y*t.y;
        im += f.x*t.y + f.y*t.x;
    }
    CIN[((pbase + c)*MM + j)*MM + kx] = make_float2(re, im);
}

// ---------------- spectral channel mix ----------------
__global__ __launch_bounds__(256) void k_spectral(
        const float* __restrict__ Wre, const float* __restrict__ Wim,
        const float2* __restrict__ CIN, float2* __restrict__ COUT) {
    int t = blockIdx.x * 256 + threadIdx.x;
    int p = t >> 10;
    int mode = t & 1023;
    const float* wr = Wre + (size_t)p * PP * 1024 + mode;
    const float* wi = Wim + (size_t)p * PP * 1024 + mode;
    float re = 0.f, im = 0.f;
    #pragma unroll 4
    for (int q = 0; q < PP; ++q) {
        float a = wr[(size_t)q * 1024];
        float b = wi[(size_t)q * 1024];
        float2 cv = CIN[q * 1024 + mode];
        re += a*cv.x - b*cv.y;
        im += a*cv.y + b*cv.x;
    }
    COUT[p * 1024 + mode] = make_float2(re, im);
}

// ---------------- inverse DFT along y ----------------
__global__ __launch_bounds__(256) void k_inv_y(
        const float2* __restrict__ COUT, float2* DA, float2* DB,
        const float* __restrict__ tiyA, const float* __restrict__ tiyB) {
    int bid = blockIdx.x;
    float2* D; const float2* tab; int Ny, pbase, c, yg;
    if (bid < PA*(HA/8)) { D = DA; tab = (const float2*)tiyA; Ny = HA; pbase = 0;
        c = bid >> 5; yg = bid & 31; }
    else { bid -= PA*(HA/8); D = DB; tab = (const float2*)tiyB; Ny = HB; pbase = PA;
        c = bid >> 4; yg = bid & 15; }
    int kx = threadIdx.x & 31;
    int y = yg * 8 + (threadIdx.x >> 5);
    float re = 0.f, im = 0.f;
    const float2* crow = COUT + (size_t)(pbase + c) * MM * MM + kx;
    #pragma unroll 8
    for (int j = 0; j < MM; ++j) {
        float2 w = crow[j * MM];
        float2 t = tab[j * Ny + y];
        re += w.x*t.x - w.y*t.y;
        im += w.x*t.y + w.y*t.x;
    }
    D[(size_t)(c*Ny + y)*MM + kx] = make_float2(re, im);
}

// ---------------- inverse DFT along x, B branch only (c2r) ----------------
__global__ __launch_bounds__(256) void k_inv_xb(
        const float2* __restrict__ DB, float* __restrict__ SB,
        const float* __restrict__ tixB) {
    __shared__ float2 ds[256];
    int r0 = blockIdx.x * 8;
    { int q = threadIdx.x >> 5, kx = threadIdx.x & 31;
      ds[q*32+kx] = DB[(size_t)(r0+q)*MM + kx]; }
    __syncthreads();
    int x = threadIdx.x & 127;
    int h = threadIdx.x >> 7;
    int base = h*4*32;
    const float2* tab = (const float2*)tixB;
    float a0=0,a1=0,a2=0,a3=0;
    for (int kx = 0; kx < MM; ++kx) {
        float2 t = tab[kx*WB + x];
        float2 d0 = ds[base+kx], d1 = ds[base+32+kx], d2 = ds[base+64+kx], d3 = ds[base+96+kx];
        a0 += d0.x*t.x - d0.y*t.y;
        a1 += d1.x*t.x - d1.y*t.y;
        a2 += d2.x*t.x - d2.y*t.y;
        a3 += d3.x*t.x - d3.y*t.y;
    }
    SB[(size_t)(r0+h*4+0)*WB + x] = a0;
    SB[(size_t)(r0+h*4+1)*WB + x] = a1;
    SB[(size_t)(r0+h*4+2)*WB + x] = a2;
    SB[(size_t)(r0+h*4+3)*WB + x] = a3;
}

// ---------------- fused A-branch tail ----------------
// per block: half of one y-row (128 px). inv-x DFT (in-register twiddle
// recurrence, c2r weights folded into D) -> 1x1 conv + gelu -> 1x1 conv +
// gelu + residual, all via LDS. grid = 512 (= HA rows x 2 halves).
__global__ __launch_bounds__(256) void k_a_tail(
        const float2* __restrict__ D, float* __restrict__ UA,
        const float* __restrict__ w1, const float* __restrict__ b1,
        const float* __restrict__ w2, const float* __restrict__ b2) {
    // LDS: buf0 [6144] = tl (conv1 out), first 3072 floats double as Dw (float2[1536])
    //      sl [6144] = inv-x output, wl [2304] transposed weights, bl [48]
    __shared__ float sm[6144 + 6144 + 2304 + 48];
    float* buf0 = sm;
    float2* Dw  = (float2*)sm;
    float* sl   = sm + 6144;
    float* wl   = sm + 12288;
    float* bl   = sm + 14592;
    int y  = blockIdx.x >> 1;
    int xh = (blockIdx.x & 1) << 7;
    int t  = threadIdx.x;

    // stage weighted D (48 ch x 32 kx) and transposed w1
    for (int idx = t; idx < 1536; idx += 256) {
        int c = idx >> 5, kx = idx & 31;
        float2 v = D[((size_t)c*HA + y)*MM + kx];
        float wgt = (kx == 0) ? 1.0f : 2.0f;
        Dw[idx] = make_float2(v.x*wgt, v.y*wgt);
    }
    for (int idx = t; idx < 2304; idx += 256) {
        int o = idx % 48, i = idx / 48;
        wl[i*48 + o] = w1[o*48 + i];
    }
    if (t < 48) bl[t] = b1[t];
    __syncthreads();

    // phase 2: inverse-x DFT; thread = (pixel, channel-half)
    {
        int xl = t & 127;
        int x  = xh + xl;
        int i0 = (t >> 7) * 24;
        float ang = 6.28318530717958647692f * (float)x / 256.0f;
        float s1, c1; __sincosf(ang, &s1, &c1);
        float twr[32], twi[32];
        twr[0] = 1.0f; twi[0] = 0.0f;
        #pragma unroll
        for (int k = 1; k < 32; ++k) {
            twr[k] = twr[k-1]*c1 - twi[k-1]*s1;
            twi[k] = twr[k-1]*s1 + twi[k-1]*c1;
        }
        for (int i = i0; i < i0 + 24; ++i) {
            const float2* dr = Dw + i*32;       // wave-uniform -> LDS broadcast
            float acc = 0.0f;
            #pragma unroll
            for (int k = 0; k < 32; ++k) {
                float2 d = dr[k];
                acc += d.x*twr[k] - d.y*twi[k];
            }
            sl[i*128 + xl] = acc;
        }
    }
    __syncthreads();

    int pp = t & 63, og = t >> 6;   // 64 pixel-pairs x 4 o-groups of 12
    // phase 3: conv1 (48->48) + gelu -> tl (overwrites Dw, dead now)
    {
        float acc[12][2];
        #pragma unroll
        for (int oo = 0; oo < 12; ++oo) { float bv = bl[og*12+oo]; acc[oo][0]=bv; acc[oo][1]=bv; }
        for (int i = 0; i < 48; ++i) {
            float2 s = *(const float2*)(sl + i*128 + pp*2);
            const float4* wv = (const float4*)(wl + i*48 + og*12);
            float wq[12];
            *(float4*)(wq+0)=wv[0]; *(float4*)(wq+4)=wv[1]; *(float4*)(wq+8)=wv[2];
            #pragma unroll
            for (int oo = 0; oo < 12; ++oo) { acc[oo][0]+=wq[oo]*s.x; acc[oo][1]+=wq[oo]*s.y; }
        }
        #pragma unroll
        for (int oo = 0; oo < 12; ++oo) {
            int o = og*12+oo;
            float2 g; g.x = gelu_f(acc[oo][0]); g.y = gelu_f(acc[oo][1]);
            *(float2*)(buf0 + o*128 + pp*2) = g;
        }
    }
    __syncthreads();
    // swap in w2
    for (int idx = t; idx < 2304; idx += 256) {
        int o = idx % 48, i = idx / 48;
        wl[i*48 + o] = w2[o*48 + i];
    }
    if (t < 48) bl[t] = b2[t];
    __syncthreads();
    // phase 4: conv2 (48->48) + gelu + residual -> UA
    {
        float acc[12][2];
        #pragma unroll
        for (int oo = 0; oo < 12; ++oo) { float bv = bl[og*12+oo]; acc[oo][0]=bv; acc[oo][1]=bv; }
        for (int i = 0; i < 48; ++i) {
            float2 s = *(const float2*)(buf0 + i*128 + pp*2);
            const float4* wv = (const float4*)(wl + i*48 + og*12);
            float wq[12];
            *(float4*)(wq+0)=wv[0]; *(float4*)(wq+4)=wv[1]; *(float4*)(wq+8)=wv[2];
            #pragma unroll
            for (int oo = 0; oo < 12; ++oo) { acc[oo][0]+=wq[oo]*s.x; acc[oo][1]+=wq[oo]*s.y; }
        }
        #pragma unroll
        for (int oo = 0; oo < 12; ++oo) {
            int o = og*12+oo;
            size_t obase = (size_t)o*NPIXA + (size_t)y*WA + xh + pp*2;
            float2 rv = *(const float2*)(UA + obase);
            float2 r;
            r.x = gelu_f(acc[oo][0]) + rv.x;
            r.y = gelu_f(acc[oo][1]) + rv.y;
            *(float2*)(UA + obase) = r;
        }
    }
}

// ---------------- B-branch 3x3 conv + gelu (+resid), prefetch-pipelined ----------------
__global__ __launch_bounds__(256) void k_conv3x3(
        const float* __restrict__ in, float* __restrict__ out,
        const float* __restrict__ w, const float* __restrict__ b,
        const float* resid) {
    __shared__ __attribute__((aligned(16))) float wl[PB*9*8];  // [ic][tap][oo(6,pad8)]
    __shared__ float bl[6];
    int o0 = blockIdx.y * 6;
    for (int idx = threadIdx.x; idx < PB*9*6; idx += 256) {
        int oo = idx % 6;
        int r = idx / 6;
        int tap = r % 9;
        int ic = r / 9;
        wl[(ic*9+tap)*8 + oo] = w[((size_t)(o0+oo)*PB + ic)*9 + tap];
    }
    if (threadIdx.x < 6) bl[threadIdx.x] = b[o0+threadIdx.x];
    __syncthreads();

    int wv = threadIdx.x >> 6;
    int lane = threadIdx.x & 63;
    int y = blockIdx.x * 4 + wv;
    int x0 = lane * 2;

    float acc[6][2];
    #pragma unroll
    for (int oo = 0; oo < 6; ++oo) { acc[oo][0]=bl[oo]; acc[oo][1]=bl[oo]; }

    // initial window for ic=0
    float win[3][4];
    {
        const float* ip = in;
        #pragma unroll
        for (int dy = 0; dy < 3; ++dy) {
            int gy = y - 1 + dy;
            float2 s;
            if (gy >= 0 && gy < HB) s = *(const float2*)(ip + gy*WB + x0);
            else { s.x = 0.f; s.y = 0.f; }
            float lft = __shfl_up(s.y, 1);  if (lane == 0)  lft = 0.f;
            float rgt = __shfl_down(s.x, 1); if (lane == 63) rgt = 0.f;
            win[dy][0]=lft; win[dy][1]=s.x; win[dy][2]=s.y; win[dy][3]=rgt;
        }
    }
    for (int ic = 0; ic < PB; ++ic) {
        // issue next-channel loads before the tap loop (latency hides under FMAs)
        float2 nx[3];
        if (ic + 1 < PB) {
            const float* ipn = in + (size_t)(ic+1)*NPIXB;
            #pragma unroll
            for (int dy = 0; dy < 3; ++dy) {
                int gy = y - 1 + dy;
                if (gy >= 0 && gy < HB) nx[dy] = *(const float2*)(ipn + gy*WB + x0);
                else { nx[dy].x = 0.f; nx[dy].y = 0.f; }
            }
        }
        const float* wb_ = wl + ic*9*8;
        #pragma unroll
        for (int tap = 0; tap < 9; ++tap) {
            int dy = tap / 3, dx = tap % 3;
            float4 w03 = *(const float4*)(wb_ + tap*8);
            float2 w45 = *(const float2*)(wb_ + tap*8 + 4);
            float s0 = win[dy][dx];
            float s1 = win[dy][dx+1];
            acc[0][0] += w03.x*s0; acc[0][1] += w03.x*s1;
            acc[1][0] += w03.y*s0; acc[1][1] += w03.y*s1;
            acc[2][0] += w03.z*s0; acc[2][1] += w03.z*s1;
            acc[3][0] += w03.w*s0; acc[3][1] += w03.w*s1;
            acc[4][0] += w45.x*s0; acc[4][1] += w45.x*s1;
            acc[5][0] += w45.y*s0; acc[5][1] += w45.y*s1;
        }
        if (ic + 1 < PB) {
            #pragma unroll
            for (int dy = 0; dy < 3; ++dy) {
                float lft = __shfl_up(nx[dy].y, 1);  if (lane == 0)  lft = 0.f;
                float rgt = __shfl_down(nx[dy].x, 1); if (lane == 63) rgt = 0.f;
                win[dy][0]=lft; win[dy][1]=nx[dy].x; win[dy][2]=nx[dy].y; win[dy][3]=rgt;
            }
        }
    }
    #pragma unroll
    for (int oo = 0; oo < 6; ++oo) {
        size_t obase = (size_t)(o0+oo)*NPIXB + (size_t)y*WB + x0;
        float2 r;
        r.x = gelu_f(acc[oo][0]);
        r.y = gelu_f(acc[oo][1]);
        if (resid) { float2 rv = *(const float2*)(resid+obase); r.x += rv.x; r.y += rv.y; }
        *(float2*)(out+obase) = r;
    }
}

// ---------------- decoder: 48->1 both branches ----------------
__global__ __launch_bounds__(256) void k_decode(
        const float* __restrict__ UA, const float* __restrict__ UB,
        const float* dwa, const float* dba,
        const float* dwb, const float* dbb, float* outp) {
    int t = blockIdx.x*256 + threadIdx.x;
    if (t < NPIXA) {
        float acc = dba[0];
        #pragma unroll 8
        for (int p = 0; p < PA; ++p) acc += dwa[p]*UA[(size_t)p*NPIXA + t];
        outp[t] = acc;
    } else {
        int u = t - NPIXA;
        float acc = dbb[0];
        #pragma unroll 8
        for (int p = 0; p < PB; ++p) acc += dwb[p]*UB[(size_t)p*NPIXB + u];
        outp[t] = acc;
    }
}

extern "C" void kernel_launch(void* const* d_in, const int* in_sizes, int n_in,
                              void* d_out, int out_size, void* d_ws, size_t ws_size,
                              hipStream_t stream) {
    const float* u_a   = (const float*)d_in[0];
    const float* x_a   = (const float*)d_in[1];
    const float* u_b   = (const float*)d_in[2];
    const float* x_b   = (const float*)d_in[3];
    const float* enc_a_w = (const float*)d_in[4];
    const float* enc_a_b = (const float*)d_in[5];
    const float* enc_b_w = (const float*)d_in[6];
    const float* enc_b_b = (const float*)d_in[7];
    const float* dec_a_w = (const float*)d_in[8];
    const float* dec_a_b = (const float*)d_in[9];
    const float* dec_b_w = (const float*)d_in[10];
    const float* dec_b_b = (const float*)d_in[11];
    const float* c1a_w = (const float*)d_in[12];
    const float* c1a_b = (const float*)d_in[13];
    const float* c2a_w = (const float*)d_in[14];
    const float* c2a_b = (const float*)d_in[15];
    const float* c1b_w = (const float*)d_in[16];
    const float* c1b_b = (const float*)d_in[17];
    const float* c2b_w = (const float*)d_in[18];
    const float* c2b_b = (const float*)d_in[19];
    const float* A_re = (const float*)d_in[20];
    const float* A_im = (const float*)d_in[21];

    float* ws = (float*)d_ws;
    size_t off = 0;
    auto alloc = [&](size_t n) { float* p = ws + off; off += n; return p; };
    float* TfxAT = alloc(MM*WA*2);
    float* TfyA  = alloc(MM*HA*2);
    float* TixA  = alloc(MM*WA*2);   // unused now, kept for layout stability
    float* TiyA  = alloc(MM*HA*2);
    float* TfxBT = alloc(MM*WB*2);
    float* TfyB  = alloc(MM*HB*2);
    float* TixB  = alloc(MM*WB*2);
    float* TiyB  = alloc(MM*HB*2);
    float* UA = alloc((size_t)PA*NPIXA);
    float* UB = alloc((size_t)PB*NPIXB);
    float* SB = alloc((size_t)PB*NPIXB);
    float* TB = alloc((size_t)PB*NPIXB);
    float2* FA = (float2*)alloc((size_t)PA*HA*MM*2);
    float2* FB = (float2*)alloc((size_t)PB*HB*MM*2);
    float2* CIN  = (float2*)alloc((size_t)PP*MM*MM*2);
    float2* COUT = (float2*)alloc((size_t)PP*MM*MM*2);
    if (off * sizeof(float) > ws_size) return;
    (void)TixA;

    k_gen_tables<<<dim3(48), dim3(256), 0, stream>>>(TfxAT,TfyA,TixA,TiyA,TfxBT,TfyB,TixB,TiyB);
    k_encode<<<dim3(320,48), dim3(256), 0, stream>>>(u_a,x_a,u_b,x_b,
        enc_a_w,enc_a_b,enc_b_w,enc_b_b, UA,UB);
    for (int l = 0; l < 4; ++l) {
        k_fwd_x<<<dim3(576), dim3(256), 32768, stream>>>(UA,UB,FA,FB,TfxAT,TfxBT);
        k_fwd_y<<<dim3(384), dim3(256), 0, stream>>>(FA,FB,CIN,TfyA,TfyB);
        k_spectral<<<dim3(384), dim3(256), 0, stream>>>(
            A_re + (size_t)l*PP*PP*MM*MM, A_im + (size_t)l*PP*PP*MM*MM, CIN, COUT);
        k_inv_y<<<dim3(2304), dim3(256), 0, stream>>>(COUT, FA, FB, TiyA, TiyB);
        k_a_tail<<<dim3(512), dim3(256), 0, stream>>>(FA, UA,
            c1a_w + (size_t)l*PA*PA, c1a_b + (size_t)l*PA,
            c2a_w + (size_t)l*PA*PA, c2a_b + (size_t)l*PA);
        k_inv_xb<<<dim3(768), dim3(256), 0, stream>>>(FB, SB, TixB);
        k_conv3x3<<<dim3(32,8), dim3(256), 0, stream>>>(SB, TB,
            c1b_w + (size_t)l*PB*PB*9, c1b_b + (size_t)l*PB, (const float*)nullptr);
        k_conv3x3<<<dim3(32,8), dim3(256), 0, stream>>>(TB, UB,
            c2b_w + (size_t)l*PB*PB*9, c2b_b + (size_t)l*PB, UB);
    }
    k_decode<<<dim3(320), dim3(256), 0, stream>>>(UA, UB,
        dec_a_w, dec_a_b, dec_b_w, dec_b_b, (float*)d_out);
}

// Round 4
// 739.983 us; speedup vs baseline: 1.7956x; 1.0008x over previous
//
#include <hip/hip_runtime.h>

#define HA 256
#define WA 256
#define HB 128
#define WB 128
#define PA 48
#define PB 48
#define PP 96
#define MM 32
#define NPIXA (HA*WA)   // 65536
#define NPIXB (HB*WB)   // 16384

__device__ __forceinline__ float gelu_f(float x) {
    float z = 0.7978845608028654f * (x + 0.044715f * x * x * x);
    float e = __expf(2.0f * z);
    return x - x / (e + 1.0f);
}

// ---------------- DFT twiddle tables ----------------
__global__ __launch_bounds__(256) void k_gen_tables(
        float* tfxAT, float* tfyA, float* tiyA,
        float* tfxBT, float* tfyB, float* tixB, float* tiyB) {
    const float TWO_PI = 6.28318530717958647692f;
    int t = blockIdx.x * 256 + threadIdx.x;
    if (t < MM * WA) {
        int k = t / WA, x = t - k * WA;
        int m = (k * x) & (WA - 1);
        float ang = TWO_PI * (float)m / (float)WA;
        float s, c; __sincosf(ang, &s, &c);
        float sc = 1.0f / (float)(HA * WA);
        tfxAT[(x*MM + k)*2]   = c * sc;
        tfxAT[(x*MM + k)*2+1] = -s * sc;
        int ky = k - 16;
        int my = (ky * x) & (HA - 1);
        float angy = TWO_PI * (float)my / (float)HA;
        float sy, cy; __sincosf(angy, &sy, &cy);
        tfyA[2*t] = cy; tfyA[2*t+1] = -sy;
        tiyA[2*t] = cy; tiyA[2*t+1] = sy;
    } else if (t < MM * WA + MM * WB) {
        int t2 = t - MM * WA;
        int k = t2 / WB, x = t2 - k * WB;
        int m = (k * x) & (WB - 1);
        float ang = TWO_PI * (float)m / (float)WB;
        float s, c; __sincosf(ang, &s, &c);
        float sc = 1.0f / (float)(HB * WB);
        tfxBT[(x*MM + k)*2]   = c * sc;
        tfxBT[(x*MM + k)*2+1] = -s * sc;
        float wgt = (k == 0) ? 1.0f : 2.0f;
        tixB[2*t2] = wgt * c; tixB[2*t2+1] = wgt * s;
        int ky = k - 16;
        int my = (ky * x) & (HB - 1);
        float angy = TWO_PI * (float)my / (float)HB;
        float sy, cy; __sincosf(angy, &sy, &cy);
        tfyB[2*t2] = cy; tfyB[2*t2+1] = -sy;
        tiyB[2*t2] = cy; tiyB[2*t2+1] = sy;
    }
}

// ---------------- encoder (1x1 conv, 3->48) ----------------
__global__ __launch_bounds__(256) void k_encode(
        const float* u_a, const float* x_a, const float* u_b, const float* x_b,
        const float* wa, const float* ba, const float* wb, const float* bb,
        float* UA, float* UB) {
    int o = blockIdx.y;
    if (blockIdx.x < NPIXA/256) {
        int pix = blockIdx.x * 256 + threadIdx.x;
        UA[(size_t)o*NPIXA + pix] = wa[o*3+0]*x_a[pix] + wa[o*3+1]*x_a[NPIXA+pix]
                                  + wa[o*3+2]*u_a[pix] + ba[o];
    } else {
        int pix = (blockIdx.x - NPIXA/256) * 256 + threadIdx.x;
        UB[(size_t)o*NPIXB + pix] = wb[o*3+0]*x_b[pix] + wb[o*3+1]*x_b[NPIXB+pix]
                                  + wb[o*3+2]*u_b[pix] + bb[o];
    }
}

// ---------------- forward DFT along x ----------------
__global__ __launch_bounds__(256) void k_fwd_x(
        const float* __restrict__ UA, const float* __restrict__ UB,
        float2* __restrict__ FA, float2* __restrict__ FB,
        const float* __restrict__ tfxAT, const float* __restrict__ tfxBT) {
    extern __shared__ float ls[];
    int bid = blockIdx.x;
    const float* U; float2* F; const float2* tT; int N;
    const int NBA = PA * HA / 32;   // 384
    if (bid < NBA) { U = UA; F = FA; tT = (const float2*)tfxAT; N = WA; }
    else { bid -= NBA; U = UB; F = FB; tT = (const float2*)tfxBT; N = WB; }
    int r0 = bid * 32;
    int tot4 = 32 * N / 4;
    const float4* src = (const float4*)(U + (size_t)r0 * N);
    for (int i = threadIdx.x; i < tot4; i += 256) ((float4*)ls)[i] = src[i];
    __syncthreads();
    int kx = threadIdx.x & 31;
    int rg = (threadIdx.x >> 5) * 4;
    float ar0=0,ai0=0,ar1=0,ai1=0,ar2=0,ai2=0,ar3=0,ai3=0;
    for (int x = 0; x < N; ++x) {
        float2 t = tT[x*MM + kx];
        float u0 = ls[(rg+0)*N + x];
        float u1 = ls[(rg+1)*N + x];
        float u2 = ls[(rg+2)*N + x];
        float u3 = ls[(rg+3)*N + x];
        ar0 += u0*t.x; ai0 += u0*t.y;
        ar1 += u1*t.x; ai1 += u1*t.y;
        ar2 += u2*t.x; ai2 += u2*t.y;
        ar3 += u3*t.x; ai3 += u3*t.y;
    }
    F[(size_t)(r0+rg+0)*MM + kx] = make_float2(ar0, ai0);
    F[(size_t)(r0+rg+1)*MM + kx] = make_float2(ar1, ai1);
    F[(size_t)(r0+rg+2)*MM + kx] = make_float2(ar2, ai2);
    F[(size_t)(r0+rg+3)*MM + kx] = make_float2(ar3, ai3);
}

// ---------------- forward DFT along y ----------------
__global__ __launch_bounds__(256) void k_fwd_y(
        const float2* __restrict__ FA, const float2* __restrict__ FB, float2* CIN,
        const float* __restrict__ tfyA, const float* __restrict__ tfyB) {
    int bid = blockIdx.x;
    const float2* F; const float2* tab; int Ny, pbase;
    if (bid < PA*4) { F = FA; tab = (const float2*)tfyA; Ny = HA; pbase = 0; }
    else { bid -= PA*4; F = FB; tab = (const float2*)tfyB; Ny = HB; pbase = PA; }
    int c = bid >> 2;
    int j = (bid & 3) * 8 + (threadIdx.x >> 5);
    int kx = threadIdx.x & 31;
    float re = 0.f, im = 0.f;
    const float2* fr = F + (size_t)c * Ny * MM + kx;
    const float2* tj = tab + j * Ny;
    #pragma unroll 4
    for (int y = 0; y < Ny; ++y) {
        float2 f = fr[y * MM];
        float2 t = tj[y];
        re += f.x*t.x - f.y*t.y;
        im += f.x*t.y + f.y*t.x;
    }
    CIN[((pbase + c)*MM + j)*MM + kx] = make_float2(re, im);
}

// ---------------- spectral channel mix: 4-way q-split partials ----------------
__global__ __launch_bounds__(256) void k_spectral(
        const float* __restrict__ Wre, const float* __restrict__ Wim,
        const float2* __restrict__ CIN, float2* __restrict__ PART) {
    int part = blockIdx.y;                 // 0..3, 24 q's each
    int t = blockIdx.x * 256 + threadIdx.x;
    int p = t >> 10;
    int mode = t & 1023;
    int q0 = part * 24;
    const float* wr = Wre + ((size_t)p * PP + q0) * 1024 + mode;
    const float* wi = Wim + ((size_t)p * PP + q0) * 1024 + mode;
    const float2* cin = CIN + q0 * 1024 + mode;
    float re = 0.f, im = 0.f;
    #pragma unroll 4
    for (int q = 0; q < 24; ++q) {
        float a = wr[(size_t)q * 1024];
        float b = wi[(size_t)q * 1024];
        float2 cv = cin[q * 1024];
        re += a*cv.x - b*cv.y;
        im += a*cv.y + b*cv.x;
    }
    PART[((size_t)part * PP + p) * 1024 + mode] = make_float2(re, im);
}

__global__ __launch_bounds__(256) void k_cred(
        const float2* __restrict__ PART, float2* __restrict__ COUT) {
    int t = blockIdx.x * 256 + threadIdx.x;   // 98304
    float2 a = PART[t];
    float2 b = PART[PP*1024 + t];
    float2 c = PART[2*PP*1024 + t];
    float2 d = PART[3*PP*1024 + t];
    COUT[t] = make_float2(a.x+b.x+c.x+d.x, a.y+b.y+c.y+d.y);
}

// ---------------- inverse DFT along y; B-path fused with inv-x -> SB ----------------
__global__ __launch_bounds__(256) void k_inv_y(
        const float2* __restrict__ COUT, float2* __restrict__ DA,
        float* __restrict__ SB,
        const float* __restrict__ tiyA, const float* __restrict__ tiyB,
        const float* __restrict__ tixB) {
    int bid = blockIdx.x;
    int t = threadIdx.x;
    if (bid < PA*(HA/8)) {
        // A path: write DA(c,y,kx)
        int c = bid >> 5, yg = bid & 31;
        int kx = t & 31;
        int y = yg * 8 + (t >> 5);
        float re = 0.f, im = 0.f;
        const float2* crow = COUT + (size_t)c * MM * MM + kx;
        const float2* tab = (const float2*)tiyA;
        #pragma unroll 8
        for (int j = 0; j < MM; ++j) {
            float2 w = crow[j * MM];
            float2 tv = tab[j * HA + y];
            re += w.x*tv.x - w.y*tv.y;
            im += w.x*tv.y + w.y*tv.x;
        }
        DA[(size_t)(c*HA + y)*MM + kx] = make_float2(re, im);
    } else {
        bid -= PA*(HA/8);
        int c = bid >> 4, yg = bid & 15;
        int kx = t & 31;
        int yr = t >> 5;
        int y = yg * 8 + yr;
        float re = 0.f, im = 0.f;
        const float2* crow = COUT + (size_t)(PA + c) * MM * MM + kx;
        const float2* tab = (const float2*)tiyB;
        #pragma unroll 8
        for (int j = 0; j < MM; ++j) {
            float2 w = crow[j * MM];
            float2 tv = tab[j * HB + y];
            re += w.x*tv.x - w.y*tv.y;
            im += w.x*tv.y + w.y*tv.x;
        }
        __shared__ float2 ds[256];
        ds[yr*32 + kx] = make_float2(re, im);
        __syncthreads();
        // inv-x c2r: 8 rows x 128 px; thread -> (x, row strided by 2)
        int x = t & 127;
        int rp = t >> 7;
        const float2* txb = (const float2*)tixB;
        #pragma unroll
        for (int r = rp; r < 8; r += 2) {
            const float2* drow = ds + r*32;
            float a = 0.f;
            #pragma unroll
            for (int k2 = 0; k2 < MM; ++k2) {
                float2 tv = txb[k2*WB + x];
                float2 d = drow[k2];
                a += d.x*tv.x - d.y*tv.y;
            }
            SB[((size_t)c*HB + yg*8 + r)*WB + x] = a;
        }
    }
}

// ---------------- fused A-branch tail ----------------
__global__ __launch_bounds__(256) void k_a_tail(
        const float2* __restrict__ D, float* __restrict__ UA,
        const float* __restrict__ w1, const float* __restrict__ b1,
        const float* __restrict__ w2, const float* __restrict__ b2) {
    __shared__ float sm[6144 + 6144 + 2304 + 48];
    float* buf0 = sm;
    float2* Dw  = (float2*)sm;
    float* sl   = sm + 6144;
    float* wl   = sm + 12288;
    float* bl   = sm + 14592;
    int y  = blockIdx.x >> 1;
    int xh = (blockIdx.x & 1) << 7;
    int t  = threadIdx.x;

    for (int idx = t; idx < 1536; idx += 256) {
        int c = idx >> 5, kx = idx & 31;
        float2 v = D[((size_t)c*HA + y)*MM + kx];
        float wgt = (kx == 0) ? 1.0f : 2.0f;
        Dw[idx] = make_float2(v.x*wgt, v.y*wgt);
    }
    for (int idx = t; idx < 2304; idx += 256) {
        int o = idx % 48, i = idx / 48;
        wl[i*48 + o] = w1[o*48 + i];
    }
    if (t < 48) bl[t] = b1[t];
    __syncthreads();

    // phase 2: inverse-x DFT (in-register twiddles, float4 LDS broadcasts)
    {
        int xl = t & 127;
        int x  = xh + xl;
        int i0 = (t >> 7) * 24;
        float ang = 6.28318530717958647692f * (float)x / 256.0f;
        float s1, c1; __sincosf(ang, &s1, &c1);
        float twr[32], twi[32];
        twr[0] = 1.0f; twi[0] = 0.0f;
        #pragma unroll
        for (int k = 1; k < 32; ++k) {
            twr[k] = twr[k-1]*c1 - twi[k-1]*s1;
            twi[k] = twr[k-1]*s1 + twi[k-1]*c1;
        }
        for (int i = i0; i < i0 + 24; ++i) {
            const float4* dr4 = (const float4*)(Dw + i*32);
            float acc = 0.0f;
            #pragma unroll
            for (int k4 = 0; k4 < 16; ++k4) {
                float4 v = dr4[k4];
                acc += v.x*twr[2*k4]   - v.y*twi[2*k4];
                acc += v.z*twr[2*k4+1] - v.w*twi[2*k4+1];
            }
            sl[i*128 + xl] = acc;
        }
    }
    __syncthreads();

    int pp = t & 63, og = t >> 6;
    {
        float acc[12][2];
        #pragma unroll
        for (int oo = 0; oo < 12; ++oo) { float bv = bl[og*12+oo]; acc[oo][0]=bv; acc[oo][1]=bv; }
        for (int i = 0; i < 48; ++i) {
            float2 s = *(const float2*)(sl + i*128 + pp*2);
            const float4* wv = (const float4*)(wl + i*48 + og*12);
            float wq[12];
            *(float4*)(wq+0)=wv[0]; *(float4*)(wq+4)=wv[1]; *(float4*)(wq+8)=wv[2];
            #pragma unroll
            for (int oo = 0; oo < 12; ++oo) { acc[oo][0]+=wq[oo]*s.x; acc[oo][1]+=wq[oo]*s.y; }
        }
        #pragma unroll
        for (int oo = 0; oo < 12; ++oo) {
            int o = og*12+oo;
            float2 g; g.x = gelu_f(acc[oo][0]); g.y = gelu_f(acc[oo][1]);
            *(float2*)(buf0 + o*128 + pp*2) = g;
        }
    }
    __syncthreads();
    for (int idx = t; idx < 2304; idx += 256) {
        int o = idx % 48, i = idx / 48;
        wl[i*48 + o] = w2[o*48 + i];
    }
    if (t < 48) bl[t] = b2[t];
    __syncthreads();
    {
        float acc[12][2];
        #pragma unroll
        for (int oo = 0; oo < 12; ++oo) { float bv = bl[og*12+oo]; acc[oo][0]=bv; acc[oo][1]=bv; }
        for (int i = 0; i < 48; ++i) {
            float2 s = *(const float2*)(buf0 + i*128 + pp*2);
            const float4* wv = (const float4*)(wl + i*48 + og*12);
            float wq[12];
            *(float4*)(wq+0)=wv[0]; *(float4*)(wq+4)=wv[1]; *(float4*)(wq+8)=wv[2];
            #pragma unroll
            for (int oo = 0; oo < 12; ++oo) { acc[oo][0]+=wq[oo]*s.x; acc[oo][1]+=wq[oo]*s.y; }
        }
        #pragma unroll
        for (int oo = 0; oo < 12; ++oo) {
            int o = og*12+oo;
            size_t obase = (size_t)o*NPIXA + (size_t)y*WA + xh + pp*2;
            float2 rv = *(const float2*)(UA + obase);
            float2 r;
            r.x = gelu_f(acc[oo][0]) + rv.x;
            r.y = gelu_f(acc[oo][1]) + rv.y;
            *(float2*)(UA + obase) = r;
        }
    }
}

// ---------------- B-branch 3x3 conv: oc-group 3, 2-deep prefetch ----------------
__global__ __launch_bounds__(256) void k_conv3x3(
        const float* __restrict__ in, float* __restrict__ out,
        const float* __restrict__ w, const float* __restrict__ b,
        const float* resid) {
    __shared__ __attribute__((aligned(16))) float wl[PB*9*4];  // [ic][tap][oo(3,pad4)]
    __shared__ float bl[3];
    int o0 = blockIdx.y * 3;
    for (int idx = threadIdx.x; idx < PB*9*3; idx += 256) {
        int oo = idx % 3;
        int r = idx / 3;
        int tap = r % 9;
        int ic = r / 9;
        wl[(ic*9+tap)*4 + oo] = w[((size_t)(o0+oo)*PB + ic)*9 + tap];
    }
    if (threadIdx.x < 3) bl[threadIdx.x] = b[o0+threadIdx.x];
    __syncthreads();

    int wv = threadIdx.x >> 6;
    int lane = threadIdx.x & 63;
    int y = blockIdx.x * 4 + wv;
    int x0 = lane * 2;

    float acc[3][2];
    #pragma unroll
    for (int oo = 0; oo < 3; ++oo) { acc[oo][0]=bl[oo]; acc[oo][1]=bl[oo]; }

    auto loadch = [&](int ic, float2* dst) {
        const float* ip = in + (size_t)ic*NPIXB;
        #pragma unroll
        for (int dy = 0; dy < 3; ++dy) {
            int gy = y - 1 + dy;
            if (gy >= 0 && gy < HB) dst[dy] = *(const float2*)(ip + gy*WB + x0);
            else { dst[dy].x = 0.f; dst[dy].y = 0.f; }
        }
    };
    float win[3][4];
    float2 rnxt[3];
    {
        float2 r0[3];
        loadch(0, r0);
        loadch(1, rnxt);
        #pragma unroll
        for (int dy = 0; dy < 3; ++dy) {
            float lft = __shfl_up(r0[dy].y, 1);  if (lane == 0)  lft = 0.f;
            float rgt = __shfl_down(r0[dy].x, 1); if (lane == 63) rgt = 0.f;
            win[dy][0]=lft; win[dy][1]=r0[dy].x; win[dy][2]=r0[dy].y; win[dy][3]=rgt;
        }
    }
    for (int ic = 0; ic < PB; ++ic) {
        float2 rfut[3];
        if (ic + 2 < PB) loadch(ic + 2, rfut);
        const float* wb_ = wl + ic*36;
        #pragma unroll
        for (int tap = 0; tap < 9; ++tap) {
            int dy = tap / 3, dx = tap % 3;
            float4 w3 = *(const float4*)(wb_ + tap*4);
            float s0 = win[dy][dx];
            float s1 = win[dy][dx+1];
            acc[0][0] += w3.x*s0; acc[0][1] += w3.x*s1;
            acc[1][0] += w3.y*s0; acc[1][1] += w3.y*s1;
            acc[2][0] += w3.z*s0; acc[2][1] += w3.z*s1;
        }
        if (ic + 1 < PB) {
            #pragma unroll
            for (int dy = 0; dy < 3; ++dy) {
                float lft = __shfl_up(rnxt[dy].y, 1);  if (lane == 0)  lft = 0.f;
                float rgt = __shfl_down(rnxt[dy].x, 1); if (lane == 63) rgt = 0.f;
                win[dy][0]=lft; win[dy][1]=rnxt[dy].x; win[dy][2]=rnxt[dy].y; win[dy][3]=rgt;
            }
            rnxt[0]=rfut[0]; rnxt[1]=rfut[1]; rnxt[2]=rfut[2];
        }
    }
    #pragma unroll
    for (int oo = 0; oo < 3; ++oo) {
        size_t obase = (size_t)(o0+oo)*NPIXB + (size_t)y*WB + x0;
        float2 r;
        r.x = gelu_f(acc[oo][0]);
        r.y = gelu_f(acc[oo][1]);
        if (resid) { float2 rv = *(const float2*)(resid+obase); r.x += rv.x; r.y += rv.y; }
        *(float2*)(out+obase) = r;
    }
}

// ---------------- decoder: 48->1 both branches ----------------
__global__ __launch_bounds__(256) void k_decode(
        const float* __restrict__ UA, const float* __restrict__ UB,
        const float* dwa, const float* dba,
        const float* dwb, const float* dbb, float* outp) {
    int t = blockIdx.x*256 + threadIdx.x;
    if (t < NPIXA) {
        float acc = dba[0];
        #pragma unroll 8
        for (int p = 0; p < PA; ++p) acc += dwa[p]*UA[(size_t)p*NPIXA + t];
        outp[t] = acc;
    } else {
        int u = t - NPIXA;
        float acc = dbb[0];
        #pragma unroll 8
        for (int p = 0; p < PB; ++p) acc += dwb[p]*UB[(size_t)p*NPIXB + u];
        outp[t] = acc;
    }
}

extern "C" void kernel_launch(void* const* d_in, const int* in_sizes, int n_in,
                              void* d_out, int out_size, void* d_ws, size_t ws_size,
                              hipStream_t stream) {
    const float* u_a   = (const float*)d_in[0];
    const float* x_a   = (const float*)d_in[1];
    const float* u_b   = (const float*)d_in[2];
    const float* x_b   = (const float*)d_in[3];
    const float* enc_a_w = (const float*)d_in[4];
    const float* enc_a_b = (const float*)d_in[5];
    const float* enc_b_w = (const float*)d_in[6];
    const float* enc_b_b = (const float*)d_in[7];
    const float* dec_a_w = (const float*)d_in[8];
    const float* dec_a_b = (const float*)d_in[9];
    const float* dec_b_w = (const float*)d_in[10];
    const float* dec_b_b = (const float*)d_in[11];
    const float* c1a_w = (const float*)d_in[12];
    const float* c1a_b = (const float*)d_in[13];
    const float* c2a_w = (const float*)d_in[14];
    const float* c2a_b = (const float*)d_in[15];
    const float* c1b_w = (const float*)d_in[16];
    const float* c1b_b = (const float*)d_in[17];
    const float* c2b_w = (const float*)d_in[18];
    const float* c2b_b = (const float*)d_in[19];
    const float* A_re = (const float*)d_in[20];
    const float* A_im = (const float*)d_in[21];

    float* ws = (float*)d_ws;
    size_t off = 0;
    auto alloc = [&](size_t n) { float* p = ws + off; off += n; return p; };
    float* TfxAT = alloc(MM*WA*2);
    float* TfyA  = alloc(MM*HA*2);
    float* TiyA  = alloc(MM*HA*2);
    float* TfxBT = alloc(MM*WB*2);
    float* TfyB  = alloc(MM*HB*2);
    float* TixB  = alloc(MM*WB*2);
    float* TiyB  = alloc(MM*HB*2);
    float* UA = alloc((size_t)PA*NPIXA);
    float* UB = alloc((size_t)PB*NPIXB);
    float* SB = alloc((size_t)PB*NPIXB);
    float* TB = alloc((size_t)PB*NPIXB);
    float2* FA = (float2*)alloc((size_t)PA*HA*MM*2);
    float2* FB = (float2*)alloc((size_t)PB*HB*MM*2);
    float2* CIN  = (float2*)alloc((size_t)PP*MM*MM*2);
    float2* COUT = (float2*)alloc((size_t)PP*MM*MM*2);
    float2* PART = (float2*)alloc((size_t)4*PP*MM*MM*2);
    if (off * sizeof(float) > ws_size) return;

    k_gen_tables<<<dim3(48), dim3(256), 0, stream>>>(TfxAT,TfyA,TiyA,TfxBT,TfyB,TixB,TiyB);
    k_encode<<<dim3(320,48), dim3(256), 0, stream>>>(u_a,x_a,u_b,x_b,
        enc_a_w,enc_a_b,enc_b_w,enc_b_b, UA,UB);
    for (int l = 0; l < 4; ++l) {
        k_fwd_x<<<dim3(576), dim3(256), 32768, stream>>>(UA,UB,FA,FB,TfxAT,TfxBT);
        k_fwd_y<<<dim3(384), dim3(256), 0, stream>>>(FA,FB,CIN,TfyA,TfyB);
        k_spectral<<<dim3(384,4), dim3(256), 0, stream>>>(
            A_re + (size_t)l*PP*PP*MM*MM, A_im + (size_t)l*PP*PP*MM*MM, CIN, PART);
        k_cred<<<dim3(384), dim3(256), 0, stream>>>(PART, COUT);
        k_inv_y<<<dim3(2304), dim3(256), 0, stream>>>(COUT, FA, SB, TiyA, TiyB, TixB);
        k_a_tail<<<dim3(512), dim3(256), 0, stream>>>(FA, UA,
            c1a_w + (size_t)l*PA*PA, c1a_b + (size_t)l*PA,
            c2a_w + (size_t)l*PA*PA, c2a_b + (size_t)l*PA);
        k_conv3x3<<<dim3(32,16), dim3(256), 0, stream>>>(SB, TB,
            c1b_w + (size_t)l*PB*PB*9, c1b_b + (size_t)l*PB, (const float*)nullptr);
        k_conv3x3<<<dim3(32,16), dim3(256), 0, stream>>>(TB, UB,
            c2b_w + (size_t)l*PB*PB*9, c2b_b + (size_t)l*PB, UB);
    }
    k_decode<<<dim3(320), dim3(256), 0, stream>>>(UA, UB,
        dec_a_w, dec_a_b, dec_b_w, dec_b_b, (float*)d_out);
}